// Round 2
// baseline (128.422 us; speedup 1.0000x reference)
//
#include <hip/hip_runtime.h>

#define B_ 2
#define F_ 4
#define T_ 1024
#define C_ 1536
#define NX_ 1536
#define CAP 64

// ---------------------------------------------------------------------------
// Kernel 1: build masks, cy counts, per-dst-channel edge lists, scale.
// Tiny work (few thousand ops) — single block with __syncthreads phases.
// ---------------------------------------------------------------------------
__global__ __launch_bounds__(1024) void build_meta(
    const int* __restrict__ wc00, const int* __restrict__ wc01, const int* __restrict__ wc02,
    const int* __restrict__ wc10, const int* __restrict__ wc11, const int* __restrict__ wc12,
    const int* __restrict__ xm0, const int* __restrict__ xm1,
    int nw0, int nw1, int nw2,
    int* __restrict__ masks,   // [2*(nw0+nw1+nw2)]
    int* __restrict__ cyInt,   // [C_]
    int* __restrict__ count,   // [C_]
    int* __restrict__ edges,   // [C_*CAP]
    float* __restrict__ scale) // [C_]
{
    const int tid = threadIdx.x;
    const int nth = blockDim.x;
    const int* wcs[6] = {wc00, wc01, wc02, wc10, wc11, wc12};
    const int* xms[2] = {xm0, xm1};
    int nws[3] = {nw0, nw1, nw2};
    int moff[6];
    int tot = 0;
    for (int f = 0; f < 6; ++f) { moff[f] = tot; tot += nws[f % 3]; }

    // zero init (ws is poisoned 0xAA before every launch)
    for (int s = tid; s < tot; s += nth) masks[s] = 0;
    for (int c = tid; c < C_; c += nth) { cyInt[c] = 0; count[c] = 0; }
    __syncthreads();

    // masks: slot s of face (i,j) survives iff s appears in xm_i[:, j]
    for (int i = 0; i < 2; ++i)
        for (int j = 0; j < 3; ++j) {
            const int f = i * 3 + j;
            const int* xm = xms[i];
            for (int p = tid; p < NX_; p += nth) {
                int s = xm[p * 3 + j];
                masks[moff[f] + s] = 1;
            }
        }
    // cy: +1 per slot per face, UNMASKED (matches reference)
    for (int f = 0; f < 6; ++f) {
        const int nw = nws[f % 3];
        const int* wc = wcs[f];
        for (int s = tid; s < nw; s += nth) atomicAdd(&cyInt[wc[s * 2 + 1]], 1);
    }
    __syncthreads();

    // edges: for slot s = ident[k]: dst = chan[s], src = chan[k], if mask[s]
    for (int f = 0; f < 6; ++f) {
        const int nw = nws[f % 3];
        const int* wc = wcs[f];
        for (int k = tid; k < nw; k += nth) {
            int s = wc[k * 2 + 0];
            if (masks[moff[f] + s]) {
                int dst = wc[s * 2 + 1];
                int src = wc[k * 2 + 1];
                int pos = atomicAdd(&count[dst], 1);
                if (pos < CAP) edges[dst * CAP + pos] = src;
            }
        }
    }
    __syncthreads();

    for (int c = tid; c < C_; c += nth) {
        int cv = cyInt[c];
        scale[c] = 1.0f / (float)(cv > 0 ? cv : 1);
    }
}

// ---------------------------------------------------------------------------
// Kernel 2: zT[b,c,t] = sum_f w_seg[f] * x[b,f,t,c]   (F-reduce + transpose)
// 64x64 (t,c) tiles, 256 threads, LDS transpose with +1 pad.
// ---------------------------------------------------------------------------
#define TILE 64
__global__ __launch_bounds__(256) void zT_kernel(
    const float* __restrict__ x, const float* __restrict__ w_seg,
    float* __restrict__ zT)
{
    __shared__ float tile[TILE][TILE + 1];
    const int b  = blockIdx.z;
    const int t0 = blockIdx.x * TILE;
    const int c0 = blockIdx.y * TILE;
    const int tx = threadIdx.x & 63;
    const int ty = threadIdx.x >> 6;   // 0..3

    const float w0 = w_seg[0], w1 = w_seg[1], w2 = w_seg[2], w3 = w_seg[3];
    const float* xb = x + (size_t)b * F_ * T_ * C_;
    const size_t fstride = (size_t)T_ * C_;

    for (int tt = ty; tt < TILE; tt += 4) {
        const size_t base = (size_t)(t0 + tt) * C_ + c0 + tx;
        float acc = w0 * xb[base]
                  + w1 * xb[base + fstride]
                  + w2 * xb[base + 2 * fstride]
                  + w3 * xb[base + 3 * fstride];
        tile[tt][tx] = acc;
    }
    __syncthreads();

    float* zb = zT + (size_t)b * C_ * T_;
    for (int cc = ty; cc < TILE; cc += 4) {
        zb[(size_t)(c0 + cc) * T_ + t0 + tx] = tile[tx][cc];
    }
}

// ---------------------------------------------------------------------------
// Kernel 3: out[b,c,t] = sigmoid(b_seg + scale[c] * sum_e zT[b, src_e, t])
// One block per (c,b); 256 threads x float4 covers T=1024. Fully coalesced.
// ---------------------------------------------------------------------------
__global__ __launch_bounds__(256) void gather_out(
    const float* __restrict__ zT,
    const int* __restrict__ edges, const int* __restrict__ count,
    const float* __restrict__ scale, const float* __restrict__ b_seg,
    float* __restrict__ out)
{
    const int c = blockIdx.x;
    const int b = blockIdx.y;
    const int n = min(count[c], CAP);
    const float sc = scale[c];
    const float bs = b_seg[0];

    const float* zb = zT + (size_t)b * C_ * T_;
    const int t = threadIdx.x * 4;

    float4 acc = make_float4(0.f, 0.f, 0.f, 0.f);
    for (int e = 0; e < n; ++e) {
        const int src = edges[c * CAP + e];
        const float4 v = *reinterpret_cast<const float4*>(zb + (size_t)src * T_ + t);
        acc.x += v.x; acc.y += v.y; acc.z += v.z; acc.w += v.w;
    }
    float4 o;
    o.x = 1.f / (1.f + expf(-(acc.x * sc + bs)));
    o.y = 1.f / (1.f + expf(-(acc.y * sc + bs)));
    o.z = 1.f / (1.f + expf(-(acc.z * sc + bs)));
    o.w = 1.f / (1.f + expf(-(acc.w * sc + bs)));
    *reinterpret_cast<float4*>(out + ((size_t)b * C_ + c) * T_ + t) = o;
}

// ---------------------------------------------------------------------------
extern "C" void kernel_launch(void* const* d_in, const int* in_sizes, int n_in,
                              void* d_out, int out_size, void* d_ws, size_t ws_size,
                              hipStream_t stream) {
    const float* x     = (const float*)d_in[0];
    const int* wc00    = (const int*)d_in[1];
    const int* wc01    = (const int*)d_in[2];
    const int* wc02    = (const int*)d_in[3];
    const int* wc10    = (const int*)d_in[4];
    const int* wc11    = (const int*)d_in[5];
    const int* wc12    = (const int*)d_in[6];
    const int* xm0     = (const int*)d_in[7];
    const int* xm1     = (const int*)d_in[8];
    const float* w_seg = (const float*)d_in[9];
    const float* b_seg = (const float*)d_in[10];
    float* out         = (float*)d_out;

    const int nw0 = in_sizes[1] / 2;
    const int nw1 = in_sizes[2] / 2;
    const int nw2 = in_sizes[3] / 2;

    char* ws = (char*)d_ws;
    size_t off = 0;
    float* zT   = (float*)(ws + off); off += (size_t)B_ * C_ * T_ * sizeof(float);
    int* edges  = (int*)(ws + off);   off += (size_t)C_ * CAP * sizeof(int);
    int* count  = (int*)(ws + off);   off += (size_t)C_ * sizeof(int);
    int* cyInt  = (int*)(ws + off);   off += (size_t)C_ * sizeof(int);
    float* scale= (float*)(ws + off); off += (size_t)C_ * sizeof(float);
    int* masks  = (int*)(ws + off);   off += (size_t)2 * (nw0 + nw1 + nw2) * sizeof(int);

    build_meta<<<1, 1024, 0, stream>>>(wc00, wc01, wc02, wc10, wc11, wc12,
                                       xm0, xm1, nw0, nw1, nw2,
                                       masks, cyInt, count, edges, scale);

    zT_kernel<<<dim3(T_ / TILE, C_ / TILE, B_), 256, 0, stream>>>(x, w_seg, zT);

    gather_out<<<dim3(C_, B_), 256, 0, stream>>>(zT, edges, count, scale, b_seg, out);
}

// Round 5
// 120.745 us; speedup vs baseline: 1.0636x; 1.0636x over previous
//
#include <hip/hip_runtime.h>

#define B_ 2
#define F_ 4
#define T_ 1024
#define C_ 1536
#define NX_ 1536
#define CAP 64
#define TILE 64
#define ZT_BLOCKS ((T_ / TILE) * (C_ / TILE) * B_)   // 16*24*2 = 768

struct MetaSh {
    int masks[4096];   // >= total slots (2488)
    int cnt[C_];
    int cy[C_];
};

union SharedU {
    float tile[TILE][TILE + 1];
    MetaSh m;
};

// ---------------------------------------------------------------------------
// Fused kernel: blocks [0, ZT_BLOCKS) compute zT[b,c,t] = sum_f w[f]*x[b,f,t,c]
// (float4 global loads/stores, LDS transpose, conflict-free scalar LDS ops).
// The LAST block builds the edge metadata entirely in LDS (runs concurrently
// with the zT blocks; stream order makes it complete before gather_out).
// ---------------------------------------------------------------------------
__global__ __launch_bounds__(256) void zt_meta(
    const float* __restrict__ x, const float* __restrict__ w_seg,
    float* __restrict__ zT,
    const int* __restrict__ wc00, const int* __restrict__ wc01, const int* __restrict__ wc02,
    const int* __restrict__ wc10, const int* __restrict__ wc11, const int* __restrict__ wc12,
    const int* __restrict__ xm0, const int* __restrict__ xm1,
    int nw0, int nw1, int nw2,
    int* __restrict__ count,   // [C_]
    int* __restrict__ edges,   // [C_*CAP]
    float* __restrict__ scale) // [C_]
{
    __shared__ SharedU sh;
    const int tid = threadIdx.x;

    if (blockIdx.x == ZT_BLOCKS) {
        // ---------------- metadata block (all state in LDS) ----------------
        const int* wcs[6] = {wc00, wc01, wc02, wc10, wc11, wc12};
        const int* xms[2] = {xm0, xm1};
        int nws[3] = {nw0, nw1, nw2};
        int moff[6];
        int tot = 0;
        for (int f = 0; f < 6; ++f) { moff[f] = tot; tot += nws[f % 3]; }

        for (int s = tid; s < 4096; s += 256) sh.m.masks[s] = 0;
        for (int c = tid; c < C_; c += 256) { sh.m.cnt[c] = 0; sh.m.cy[c] = 0; }
        __syncthreads();

        // masks: slot s of face (i,j) survives iff s appears in xm_i[:, j]
        for (int i = 0; i < 2; ++i)
            for (int j = 0; j < 3; ++j) {
                const int f = i * 3 + j;
                const int* xm = xms[i];
                for (int p = tid; p < NX_; p += 256)
                    sh.m.masks[moff[f] + xm[p * 3 + j]] = 1;
            }
        __syncthreads();

        // cy (unmasked, matches reference) + edge lists
        for (int f = 0; f < 6; ++f) {
            const int nw = nws[f % 3];
            const int* wc = wcs[f];
            for (int k = tid; k < nw; k += 256) {
                const int src = wc[k * 2 + 1];
                atomicAdd(&sh.m.cy[src], 1);
                const int s = wc[k * 2 + 0];
                if (sh.m.masks[moff[f] + s]) {
                    const int dst = wc[s * 2 + 1];
                    const int pos = atomicAdd(&sh.m.cnt[dst], 1);
                    if (pos < CAP) edges[dst * CAP + pos] = src;
                }
            }
        }
        __syncthreads();

        for (int c = tid; c < C_; c += 256) {
            count[c] = sh.m.cnt[c];
            const int cv = sh.m.cy[c];
            scale[c] = 1.0f / (float)(cv > 0 ? cv : 1);
        }
        return;
    }

    // -------------------------- zT transpose blocks ------------------------
    const int bid  = blockIdx.x;
    const int tpb  = T_ / TILE;                    // 16
    const int b    = bid / (tpb * (C_ / TILE));
    const int rem  = bid % (tpb * (C_ / TILE));
    const int t0   = (rem % tpb) * TILE;
    const int c0   = (rem / tpb) * TILE;

    const int lo = tid & 15;        // 0..15
    const int hi = tid >> 4;        // 0..15

    const float w0 = w_seg[0], w1 = w_seg[1], w2 = w_seg[2], w3 = w_seg[3];
    const float* xb = x + (size_t)b * F_ * T_ * C_;
    const size_t fs = (size_t)T_ * C_;

    // load: thread covers (t-row = p*16+hi, c-quad = lo*4); float4 global loads
    #pragma unroll
    for (int p = 0; p < 4; ++p) {
        const int tt = p * 16 + hi;
        const size_t base = (size_t)(t0 + tt) * C_ + c0 + lo * 4;
        const float4 a0 = *reinterpret_cast<const float4*>(xb + base);
        const float4 a1 = *reinterpret_cast<const float4*>(xb + base + fs);
        const float4 a2 = *reinterpret_cast<const float4*>(xb + base + 2 * fs);
        const float4 a3 = *reinterpret_cast<const float4*>(xb + base + 3 * fs);
        // scalar LDS stores: bank = (tt + 4*lo + i) % 32 -> 2-way, free
        sh.tile[tt][lo * 4 + 0] = w0 * a0.x + w1 * a1.x + w2 * a2.x + w3 * a3.x;
        sh.tile[tt][lo * 4 + 1] = w0 * a0.y + w1 * a1.y + w2 * a2.y + w3 * a3.y;
        sh.tile[tt][lo * 4 + 2] = w0 * a0.z + w1 * a1.z + w2 * a2.z + w3 * a3.z;
        sh.tile[tt][lo * 4 + 3] = w0 * a0.w + w1 * a1.w + w2 * a2.w + w3 * a3.w;
    }
    __syncthreads();

    // store: thread covers (c-row = p*16+hi, t-quad = lo*4); float4 global stores
    float* zb = zT + (size_t)b * C_ * T_;
    #pragma unroll
    for (int p = 0; p < 4; ++p) {
        const int cr = p * 16 + hi;
        const int t4 = lo * 4;
        float4 o;
        o.x = sh.tile[t4 + 0][cr];   // bank = (4*lo + i + cr) % 32 -> 2-way, free
        o.y = sh.tile[t4 + 1][cr];
        o.z = sh.tile[t4 + 2][cr];
        o.w = sh.tile[t4 + 3][cr];
        *reinterpret_cast<float4*>(zb + (size_t)(c0 + cr) * T_ + t0 + t4) = o;
    }
}

// ---------------------------------------------------------------------------
// out[b,c,t] = sigmoid(b_seg + scale[c] * sum_e zT[b, src_e, t])
// ---------------------------------------------------------------------------
__global__ __launch_bounds__(256) void gather_out(
    const float* __restrict__ zT,
    const int* __restrict__ edges, const int* __restrict__ count,
    const float* __restrict__ scale, const float* __restrict__ b_seg,
    float* __restrict__ out)
{
    const int c = blockIdx.x;
    const int b = blockIdx.y;
    const int n = min(count[c], CAP);
    const float sc = scale[c];
    const float bs = b_seg[0];

    const float* zb = zT + (size_t)b * C_ * T_;
    const int t = threadIdx.x * 4;

    float4 acc = make_float4(0.f, 0.f, 0.f, 0.f);
    for (int e = 0; e < n; ++e) {
        const int src = edges[c * CAP + e];
        const float4 v = *reinterpret_cast<const float4*>(zb + (size_t)src * T_ + t);
        acc.x += v.x; acc.y += v.y; acc.z += v.z; acc.w += v.w;
    }
    float4 o;
    o.x = 1.f / (1.f + expf(-(acc.x * sc + bs)));
    o.y = 1.f / (1.f + expf(-(acc.y * sc + bs)));
    o.z = 1.f / (1.f + expf(-(acc.z * sc + bs)));
    o.w = 1.f / (1.f + expf(-(acc.w * sc + bs)));
    *reinterpret_cast<float4*>(out + ((size_t)b * C_ + c) * T_ + t) = o;
}

// ---------------------------------------------------------------------------
extern "C" void kernel_launch(void* const* d_in, const int* in_sizes, int n_in,
                              void* d_out, int out_size, void* d_ws, size_t ws_size,
                              hipStream_t stream) {
    const float* x     = (const float*)d_in[0];
    const int* wc00    = (const int*)d_in[1];
    const int* wc01    = (const int*)d_in[2];
    const int* wc02    = (const int*)d_in[3];
    const int* wc10    = (const int*)d_in[4];
    const int* wc11    = (const int*)d_in[5];
    const int* wc12    = (const int*)d_in[6];
    const int* xm0     = (const int*)d_in[7];
    const int* xm1     = (const int*)d_in[8];
    const float* w_seg = (const float*)d_in[9];
    const float* b_seg = (const float*)d_in[10];
    float* out         = (float*)d_out;

    const int nw0 = in_sizes[1] / 2;
    const int nw1 = in_sizes[2] / 2;
    const int nw2 = in_sizes[3] / 2;

    char* ws = (char*)d_ws;
    size_t off = 0;
    float* zT    = (float*)(ws + off); off += (size_t)B_ * C_ * T_ * sizeof(float);
    int* edges   = (int*)(ws + off);   off += (size_t)C_ * CAP * sizeof(int);
    int* count   = (int*)(ws + off);   off += (size_t)C_ * sizeof(int);
    float* scale = (float*)(ws + off); off += (size_t)C_ * sizeof(float);

    zt_meta<<<ZT_BLOCKS + 1, 256, 0, stream>>>(
        x, w_seg, zT,
        wc00, wc01, wc02, wc10, wc11, wc12,
        xm0, xm1, nw0, nw1, nw2,
        count, edges, scale);

    gather_out<<<dim3(C_, B_), 256, 0, stream>>>(zT, edges, count, scale, b_seg, out);
}

// Round 6
// 115.920 us; speedup vs baseline: 1.1079x; 1.0416x over previous
//
#include <hip/hip_runtime.h>

#define B_ 2
#define F_ 4
#define T_ 1024
#define C_ 1536
#define NX_ 1536
#define CAP 12               // max edges per dst channel (Poisson(1.56); P(>12)~1e-9)
#define TT 16                // t-rows per block
#define ZPAD 1540            // z row stride in floats: 16B-aligned, %32==4 bank skew
#define NBLK ((T_ / TT) * B_)   // 64 * 2 = 128 blocks

__device__ __forceinline__ float sigmoidf_(float v) {
    return 1.0f / (1.0f + __expf(-v));
}

// ---------------------------------------------------------------------------
// Single fused kernel. Block = (b, 16-row t-tile).
// Phase 1: z[tt][c] = sum_f w[f] * x[b,f,t0+tt,c]  staged in LDS (all C).
// Phase 2: redundant per-block meta build (masks, cy, per-dst edge lists) in LDS.
// Phase 3: out[b,c,t] = sigmoid(b_seg + (1/max(cy,1)) * sum_e z[t][src_e]).
// No workspace, no intermediate global traffic: read x once, write out once.
// ---------------------------------------------------------------------------
__global__ __launch_bounds__(1024) void fused_kernel(
    const float* __restrict__ x, const float* __restrict__ w_seg,
    const float* __restrict__ b_seg,
    const int* __restrict__ wc00, const int* __restrict__ wc01, const int* __restrict__ wc02,
    const int* __restrict__ wc10, const int* __restrict__ wc11, const int* __restrict__ wc12,
    const int* __restrict__ xm0, const int* __restrict__ xm1,
    int nw0, int nw1, int nw2,
    float* __restrict__ out)
{
    __shared__ float z[TT][ZPAD];                 // 98,560 B
    __shared__ int cy[C_];                        //  6,144 B
    __shared__ int cnt[C_];                       //  6,144 B
    __shared__ unsigned short edges[C_][CAP];     // 36,864 B
    __shared__ unsigned int mask[16];             //     64 B
                                                  // total ~147.8 KB (<160 KB/CU)
    const int tid = threadIdx.x;
    const int b   = blockIdx.x / (T_ / TT);
    const int t0  = (blockIdx.x % (T_ / TT)) * TT;

    // ------------------- phase 1: x -> z (LDS), float4 loads ----------------
    const float w0 = w_seg[0], w1 = w_seg[1], w2 = w_seg[2], w3 = w_seg[3];
    const float* xb = x + (size_t)b * F_ * T_ * C_;
    const size_t fs = (size_t)T_ * C_;

    // 16 rows x 384 float4-quads = 6144 items; 1024 threads x 6 iters.
    // 384 quads/row = exactly 6 waves: every wave reads 1 KiB contiguous.
    #pragma unroll
    for (int it = 0; it < 6; ++it) {
        const int idx = tid + it * 1024;
        const int tt  = idx / 384;
        const int cq  = idx - tt * 384;
        const size_t base = (size_t)(t0 + tt) * C_ + cq * 4;
        const float4 a0 = *reinterpret_cast<const float4*>(xb + base);
        const float4 a1 = *reinterpret_cast<const float4*>(xb + base + fs);
        const float4 a2 = *reinterpret_cast<const float4*>(xb + base + 2 * fs);
        const float4 a3 = *reinterpret_cast<const float4*>(xb + base + 3 * fs);
        float4 zv;
        zv.x = w0 * a0.x + w1 * a1.x + w2 * a2.x + w3 * a3.x;
        zv.y = w0 * a0.y + w1 * a1.y + w2 * a2.y + w3 * a3.y;
        zv.z = w0 * a0.z + w1 * a1.z + w2 * a2.z + w3 * a3.z;
        zv.w = w0 * a0.w + w1 * a1.w + w2 * a2.w + w3 * a3.w;
        *reinterpret_cast<float4*>(&z[tt][cq * 4]) = zv;   // 16B-aligned (ZPAD*4%16==0)
    }
    // meta accumulators init (used by phase 2 atomics)
    for (int c = tid; c < C_; c += 1024) { cy[c] = 0; cnt[c] = 0; }
    __syncthreads();

    // ------------------- phase 2: redundant meta build ----------------------
    const int* wcs[6] = {wc00, wc01, wc02, wc10, wc11, wc12};
    const int* xms[2] = {xm0, xm1};
    const int nws[3]  = {nw0, nw1, nw2};

    for (int f = 0; f < 6; ++f) {
        if (tid < 16) mask[tid] = 0u;
        __syncthreads();
        const int jj = f % 3;
        const int* xm = xms[f / 3];
        for (int p = tid; p < NX_; p += 1024) {
            const int s = xm[p * 3 + jj];
            atomicOr(&mask[s >> 5], 1u << (s & 31));
        }
        __syncthreads();
        const int nw = nws[jj];
        const int* wc = wcs[f];
        for (int k = tid; k < nw; k += 1024) {
            const int s    = wc[k * 2 + 0];   // ident[k] (a permutation of [0,nw))
            const int srcc = wc[k * 2 + 1];   // chan[k]
            atomicAdd(&cy[srcc], 1);          // unmasked, matches reference
            if ((mask[s >> 5] >> (s & 31)) & 1u) {
                const int dst = wc[s * 2 + 1];             // chan[s]
                const int pos = atomicAdd(&cnt[dst], 1);
                if (pos < CAP) edges[dst][pos] = (unsigned short)srcc;
            }
        }
        __syncthreads();   // also orders z writes before phase 3 (last iter)
    }

    // ------------------- phase 3: gather + sigmoid + store ------------------
    const float bs = b_seg[0];
    float* ob = out + (size_t)b * C_ * T_;

    // 1536 c x 4 t-quads = 6144 items; 1024 threads x 6 iters.
    // 4-lane clusters write 64 B contiguous per c-row.
    #pragma unroll
    for (int it = 0; it < 6; ++it) {
        const int idx = tid + it * 1024;
        const int c   = idx >> 2;
        const int tq  = idx & 3;
        const int n   = min(cnt[c], CAP);
        const float inv = 1.0f / (float)max(cy[c], 1);
        const int tb = tq * 4;
        float4 acc = make_float4(0.f, 0.f, 0.f, 0.f);
        for (int e = 0; e < n; ++e) {
            const int src = edges[c][e];
            acc.x += z[tb + 0][src];
            acc.y += z[tb + 1][src];
            acc.z += z[tb + 2][src];
            acc.w += z[tb + 3][src];
        }
        float4 o;
        o.x = sigmoidf_(acc.x * inv + bs);
        o.y = sigmoidf_(acc.y * inv + bs);
        o.z = sigmoidf_(acc.z * inv + bs);
        o.w = sigmoidf_(acc.w * inv + bs);
        *reinterpret_cast<float4*>(&ob[(size_t)c * T_ + t0 + tb]) = o;
    }
}

// ---------------------------------------------------------------------------
extern "C" void kernel_launch(void* const* d_in, const int* in_sizes, int n_in,
                              void* d_out, int out_size, void* d_ws, size_t ws_size,
                              hipStream_t stream) {
    const float* x     = (const float*)d_in[0];
    const int* wc00    = (const int*)d_in[1];
    const int* wc01    = (const int*)d_in[2];
    const int* wc02    = (const int*)d_in[3];
    const int* wc10    = (const int*)d_in[4];
    const int* wc11    = (const int*)d_in[5];
    const int* wc12    = (const int*)d_in[6];
    const int* xm0     = (const int*)d_in[7];
    const int* xm1     = (const int*)d_in[8];
    const float* w_seg = (const float*)d_in[9];
    const float* b_seg = (const float*)d_in[10];
    float* out         = (float*)d_out;

    const int nw0 = in_sizes[1] / 2;
    const int nw1 = in_sizes[2] / 2;
    const int nw2 = in_sizes[3] / 2;

    fused_kernel<<<NBLK, 1024, 0, stream>>>(
        x, w_seg, b_seg,
        wc00, wc01, wc02, wc10, wc11, wc12,
        xm0, xm1, nw0, nw1, nw2,
        out);
}

// Round 9
// 110.374 us; speedup vs baseline: 1.1635x; 1.0502x over previous
//
#include <hip/hip_runtime.h>

#define B_ 2
#define F_ 4
#define T_ 1024
#define C_ 1536
#define NX_ 1536
#define CAP 12               // max edges per dst channel (Poisson(~1.6); P(>12)~1e-9)
#define TT 8                 // t-rows per block
#define ZPAD 1540            // z row stride in floats: 16B-aligned, %32==4 bank skew
#define NBLK ((T_ / TT) * B_)   // 128 * 2 = 256 blocks -> 1 per CU, full chip

__device__ __forceinline__ float sigmoidf_(float v) {
    return 1.0f / (1.0f + __expf(-v));
}

// ---------------------------------------------------------------------------
// Single fused kernel, one block per (b, 8-row t-tile), 256 blocks total.
// Phase A: masks for all 6 faces in parallel (one atomicOr pass).
// Phase B: z[tt][c] = sum_f w[f] * x[b,f,t0+tt,c] staged in LDS (all C).
// Phase C: flattened edge/cy build (single pass over all 6 faces' wc).
// Phase D: out[b,c,t] = sigmoid(b_seg + (1/max(cy,1)) * sum_e z[t][src_e]).
// 3 barriers total. Read x once, write out once: 63 MB minimum traffic.
// ---------------------------------------------------------------------------
__global__ __launch_bounds__(1024) void fused_kernel(
    const float* __restrict__ x, const float* __restrict__ w_seg,
    const float* __restrict__ b_seg,
    const int* __restrict__ wc00, const int* __restrict__ wc01, const int* __restrict__ wc02,
    const int* __restrict__ wc10, const int* __restrict__ wc11, const int* __restrict__ wc12,
    const int* __restrict__ xm0, const int* __restrict__ xm1,
    int nw0, int nw1, int nw2,
    float* __restrict__ out)
{
    __shared__ float z[TT][ZPAD];                 // 49,280 B
    __shared__ int cy[C_];                        //  6,144 B
    __shared__ int cnt[C_];                       //  6,144 B
    __shared__ unsigned short edges[C_][CAP];     // 36,864 B
    __shared__ unsigned int masks[6][16];         //    384 B
                                                  // total ~98.8 KB (<160 KB/CU)
    const int tid = threadIdx.x;
    const int b   = blockIdx.x / (T_ / TT);
    const int t0  = (blockIdx.x % (T_ / TT)) * TT;

    // ---- init LDS accumulators ----
    if (tid < 96) masks[tid >> 4][tid & 15] = 0u;
    for (int c = tid; c < C_; c += 1024) { cy[c] = 0; cnt[c] = 0; }
    __syncthreads();

    // ---- phase A: all-face masks in one pass (atomicOr, no ordering) ----
    for (int p = tid; p < 6 * NX_; p += 1024) {
        const int f = p / NX_;          // magic-mul by compiler
        const int q = p - f * NX_;
        const int j = (f < 3) ? f : f - 3;
        const int* xm = (f < 3) ? xm0 : xm1;
        const int s = xm[q * 3 + j];
        atomicOr(&masks[f][s >> 5], 1u << (s & 31));
    }

    // ---- phase B: x -> z (LDS), float4 loads ----
    const float w0 = w_seg[0], w1 = w_seg[1], w2 = w_seg[2], w3 = w_seg[3];
    const float* xb = x + (size_t)b * F_ * T_ * C_;
    const size_t fs = (size_t)T_ * C_;

    // 8 rows x 384 float4-quads = 3072 items; 1024 threads x 3 iters.
    #pragma unroll
    for (int it = 0; it < 3; ++it) {
        const int idx = tid + it * 1024;
        const int tt  = idx / 384;
        const int cq  = idx - tt * 384;
        const size_t base = (size_t)(t0 + tt) * C_ + cq * 4;
        const float4 a0 = *reinterpret_cast<const float4*>(xb + base);
        const float4 a1 = *reinterpret_cast<const float4*>(xb + base + fs);
        const float4 a2 = *reinterpret_cast<const float4*>(xb + base + 2 * fs);
        const float4 a3 = *reinterpret_cast<const float4*>(xb + base + 3 * fs);
        float4 zv;
        zv.x = w0 * a0.x + w1 * a1.x + w2 * a2.x + w3 * a3.x;
        zv.y = w0 * a0.y + w1 * a1.y + w2 * a2.y + w3 * a3.y;
        zv.z = w0 * a0.z + w1 * a1.z + w2 * a2.z + w3 * a3.z;
        zv.w = w0 * a0.w + w1 * a1.w + w2 * a2.w + w3 * a3.w;
        *reinterpret_cast<float4*>(&z[tt][cq * 4]) = zv;   // 16B-aligned
    }
    __syncthreads();   // masks + z complete

    // ---- phase C: flattened edge/cy build over all 6 faces ----
    const int tot = 2 * (nw0 + nw1 + nw2);
    for (int p = tid; p < tot; p += 1024) {
        int r = p, f;
        const int* wc;
        if (r < nw0) { f = 0; wc = wc00; }
        else { r -= nw0;
        if (r < nw1) { f = 1; wc = wc01; }
        else { r -= nw1;
        if (r < nw2) { f = 2; wc = wc02; }
        else { r -= nw2;
        if (r < nw0) { f = 3; wc = wc10; }
        else { r -= nw0;
        if (r < nw1) { f = 4; wc = wc11; }
        else { r -= nw1; f = 5; wc = wc12; } } } } }
        const int s    = wc[r * 2 + 0];   // ident[r] (permutation of [0,nw))
        const int srcc = wc[r * 2 + 1];   // chan[r]
        atomicAdd(&cy[srcc], 1);          // unmasked, matches reference
        if ((masks[f][s >> 5] >> (s & 31)) & 1u) {
            const int dst = wc[s * 2 + 1];             // chan[s]
            const int pos = atomicAdd(&cnt[dst], 1);
            if (pos < CAP) edges[dst][pos] = (unsigned short)srcc;
        }
    }
    __syncthreads();

    // ---- phase D: gather + sigmoid + store ----
    const float bs = b_seg[0];
    float* ob = out + (size_t)b * C_ * T_;

    // 1536 c x 2 t-quads = 3072 items; 1024 threads x 3 iters.
    #pragma unroll
    for (int it = 0; it < 3; ++it) {
        const int idx = tid + it * 1024;
        const int c   = idx >> 1;
        const int tq  = idx & 1;
        const int n   = min(cnt[c], CAP);
        const float inv = 1.0f / (float)max(cy[c], 1);
        const int tb = tq * 4;
        float4 acc = make_float4(0.f, 0.f, 0.f, 0.f);
        for (int e = 0; e < n; ++e) {
            const int src = edges[c][e];
            acc.x += z[tb + 0][src];
            acc.y += z[tb + 1][src];
            acc.z += z[tb + 2][src];
            acc.w += z[tb + 3][src];
        }
        float4 o;
        o.x = sigmoidf_(acc.x * inv + bs);
        o.y = sigmoidf_(acc.y * inv + bs);
        o.z = sigmoidf_(acc.z * inv + bs);
        o.w = sigmoidf_(acc.w * inv + bs);
        *reinterpret_cast<float4*>(&ob[(size_t)c * T_ + t0 + tb]) = o;
    }
}

// ---------------------------------------------------------------------------
extern "C" void kernel_launch(void* const* d_in, const int* in_sizes, int n_in,
                              void* d_out, int out_size, void* d_ws, size_t ws_size,
                              hipStream_t stream) {
    const float* x     = (const float*)d_in[0];
    const int* wc00    = (const int*)d_in[1];
    const int* wc01    = (const int*)d_in[2];
    const int* wc02    = (const int*)d_in[3];
    const int* wc10    = (const int*)d_in[4];
    const int* wc11    = (const int*)d_in[5];
    const int* wc12    = (const int*)d_in[6];
    const int* xm0     = (const int*)d_in[7];
    const int* xm1     = (const int*)d_in[8];
    const float* w_seg = (const float*)d_in[9];
    const float* b_seg = (const float*)d_in[10];
    float* out         = (float*)d_out;

    const int nw0 = in_sizes[1] / 2;
    const int nw1 = in_sizes[2] / 2;
    const int nw2 = in_sizes[3] / 2;

    fused_kernel<<<NBLK, 1024, 0, stream>>>(
        x, w_seg, b_seg,
        wc00, wc01, wc02, wc10, wc11, wc12,
        xm0, xm1, nw0, nw1, nw2,
        out);
}